// Round 2
// baseline (2072.242 us; speedup 1.0000x reference)
//
#include <hip/hip_runtime.h>
#include <math.h>

#define SEQ   2048
#define BATCH 128
#define HID   256
#define NCH   16   // k-chunks
#define KCH   16   // floats per chunk
#define VST   20   // chunk stride in floats (80B): 16 chunk bases -> 8 bank
                   // quads x 2 addrs = 2-way max on b128 reads (free, m136)

// dst = src's value from lane (lane perm pattern) via DPP (VALU pipe, no LDS).
// 0xB1 = quad_perm [1,0,3,2] (xor1); 0x4E = quad_perm [2,3,0,1] (xor2);
// 0x121/0x122/0x124/0x128 = row_ror:1/2/4/8 within each 16-lane row.
// ror8 == xor8 within 16 lanes; ror4 == xor4 HERE because after the ror8
// fold lanes l and l^8 are bitwise duplicates (lane l+4's rotate source
// l+8.. is the dup of the true xor partner l^4). Validated round 1.
template <int CTRL>
__device__ __forceinline__ float dpp_mov(float x) {
    return __int_as_float(__builtin_amdgcn_update_dpp(
        __float_as_int(x), __float_as_int(x), CTRL, 0xF, 0xF, false));
}

// One block (512 threads, 8 waves, 2 waves/SIMD) per batch element. fp32.
// Thread (R=tid>>4, l=tid&15): k-chunk [16l,16l+16), rows 8R+((tid&7)^j),
// j=0..7 -> 128 weight fp32 per thread. Reduce is all-DPP (no LDS in tail).
// Threads tid and tid^8 duplicate the same row bitwise-identically.
// v = 2h-1 fp32, double-buffered, ONE __syncthreads()/step (round-1 lesson:
// custom asm barriers + sched_barrier(0) cost −42%, m141 pathology — the
// compiler's own barrier scheduling is near-optimal).
// DEFERRED STORES (new this round): global stores of h[t-1] and y[t-1] are
// issued at the TOP of step t, right after the barrier. The vmcnt(0) drain
// inside the NEXT __syncthreads then waits on a ~1300-cycle-old store (acked,
// free) instead of a ~50-cycle-old one (~250 cyc stall every step).
// y head FUSED (validated round 1): p = h*W0[row]; ror4/ror2/ror1 leaves each
// 16-group's 8-row partial at its lane0 -> 32 partials/step in LDS (dbuf);
// wave ((t-1)&7) sums them next step and stores y[t-1]. No head kernel.
__global__ __launch_bounds__(512) __attribute__((amdgpu_waves_per_eu(2, 2)))
void rnn_scan_kernel(const float* __restrict__ x,        // (SEQ, BATCH)
                     const float* __restrict__ h0,       // (BATCH, HID)
                     const float* __restrict__ W_ih,     // (HID, 1)
                     const float* __restrict__ W_hh,     // (HID, HID)
                     const float* __restrict__ W_hh_b,   // (HID, HID)
                     const float* __restrict__ b_h,      // (HID,)
                     const int*   __restrict__ context,  // scalar
                     const float* __restrict__ Wout,     // (OUT, HID), row 0
                     const float* __restrict__ bias,     // (OUT,), [0]
                     float*       __restrict__ out_hs,   // (BATCH, SEQ, HID)
                     float*       __restrict__ out_y)    // (BATCH, SEQ)
{
    const int b   = blockIdx.x;
    const int tid = threadIdx.x;
    const int R   = tid >> 4;    // row-group: rows [8R, 8R+8)
    const int l   = tid & 15;    // k-chunk index
    const int l7  = tid & 7;
    const int row = 8 * R + l7;  // row this thread owns after the reduce
    const int w   = tid >> 6;    // wave id 0..7

    __shared__ __align__(16) float v_lds[2][NCH * VST];
    __shared__ float x_lds[SEQ];
    __shared__ __align__(16) float ypart[2][32];  // per-16-group y partials

    for (int t = tid; t < SEQ; t += 512)
        x_lds[t] = x[t * BATCH + b];

    const float ctx = (float)context[0];

    // wreg[j][c] = W_eff[8R + (l7^j)][16l + 4c .. +3]  (XOR-ordered rows)
    float4 wreg[8][4];
    #pragma unroll
    for (int j = 0; j < 8; ++j) {
        const int rj = 8 * R + (l7 ^ j);
        const float* wp = W_hh   + (size_t)rj * HID + KCH * l;
        const float* bp = W_hh_b + (size_t)rj * HID + KCH * l;
        #pragma unroll
        for (int c = 0; c < 4; ++c) {
            const float4 a = *(const float4*)(wp + 4 * c);
            const float4 d = *(const float4*)(bp + 4 * c);
            wreg[j][c] = make_float4(a.x + ctx * d.x, a.y + ctx * d.y,
                                     a.z + ctx * d.z, a.w + ctx * d.w);
        }
    }

    const float winj = W_ih[row];
    const float bhj  = b_h[row];
    const float w0   = Wout[row];   // W[0, row]
    const float b0   = bias[0];

    const int voff = VST * (row >> 4) + (row & 15);
    v_lds[0][voff] = 2.f * h0[(size_t)b * HID + row] - 1.f;  // dup-safe

    float* outp = out_hs + (size_t)b * SEQ * HID + row;
    float* yp   = out_y  + (size_t)b * SEQ;

    const float4* vr0 = (const float4*)(v_lds[0] + VST * l);  // 80B-stride
    const float4* vr1 = (const float4*)(v_lds[1] + VST * l);

    float h_prev = 0.f;  // loop-carried: h[t-1], stored at top of step t

    __syncthreads();  // v[0] + x_lds ready

    auto step = [&](int t, const float4* __restrict__ vr,
                    float* __restrict__ vw, int pb) {
        // ---- deferred stores for t-1: issued just after the barrier, so
        // they are long-acked by the time the NEXT barrier drains vmcnt.
        const int prev = t - 1;
        if (prev >= 0) {
            if ((tid & 8) == 0)
                outp[(size_t)prev * HID] = h_prev;   // 32 lanes/wave, coalesced 8-runs
            if (w == (prev & 7)) {
                const float4* pp = (const float4*)(ypart[pb ^ 1]);
                float s = 0.f;
                #pragma unroll
                for (int u = 0; u < 8; ++u) {
                    const float4 a = pp[u];
                    s += (a.x + a.y) + (a.z + a.w);
                }
                if ((tid & 63) == 0) yp[prev] = s + b0;
            }
        }

        float q[8] = {0.f, 0.f, 0.f, 0.f, 0.f, 0.f, 0.f, 0.f};
        #pragma unroll
        for (int c = 0; c < 4; ++c) {
            const float4 v4 = vr[c];
            #pragma unroll
            for (int j = 0; j < 8; ++j) {
                const float4 wv = wreg[j][c];
                q[j] += wv.x * v4.x;
                q[j] += wv.y * v4.y;
                q[j] += wv.z * v4.z;
                q[j] += wv.w * v4.w;
            }
        }
        // Fold l <-> l^8: same rows, complementary k-halves (establishes
        // the lane<->lane^8 duplicate structure).
        #pragma unroll
        for (int j = 0; j < 8; ++j) q[j] += dpp_mov<0x128>(q[j]);
        // XOR transpose-reduce, all-DPP (quad_perm xor1/xor2 preserve the
        // +-8 dup, so the final xor4 is a plain ror4).
        q[0] += dpp_mov<0xB1>(q[1]);
        q[2] += dpp_mov<0xB1>(q[3]);
        q[4] += dpp_mov<0xB1>(q[5]);
        q[6] += dpp_mov<0xB1>(q[7]);
        q[0] += dpp_mov<0x4E>(q[2]);
        q[4] += dpp_mov<0x4E>(q[6]);
        q[0] += dpp_mov<0x124>(q[4]);
        // q[0] = full dot for row 8R + l7 (dup in tid and tid^8)

        const float pre = q[0] + bhj + x_lds[t] * winj;
        const float h = 1.f / (1.f + __expf(-pre));
        vw[voff] = 2.f * h - 1.f;                 // dup write, same value
        h_prev = h;                               // global store deferred

        // y partial: rotate-reduce 8 distinct rows of this 16-lane group
        // (lanes 8..15 are duplicates; lane0 sums each row exactly once).
        float p = h * w0;
        p += dpp_mov<0x124>(p);   // +ror4
        p += dpp_mov<0x122>(p);   // +ror2
        p += dpp_mov<0x121>(p);   // +ror1 -> lane0: sum of rows 8R..8R+7
        if ((tid & 15) == 0) ypart[pb][tid >> 4] = p;

        __syncthreads();  // v for t+1 + partials ready; buffers fully read
    };

    for (int t = 0; t < SEQ; t += 2) {
        step(t,     vr0, v_lds[1], 0);
        step(t + 1, vr1, v_lds[0], 1);
    }

    // Tail: store h[SEQ-1] and finalize y[SEQ-1] (ypart[1] visible via the
    // loop's trailing barrier).
    if ((tid & 8) == 0)
        outp[(size_t)(SEQ - 1) * HID] = h_prev;
    if (w == ((SEQ - 1) & 7)) {
        const float4* pp = (const float4*)(ypart[1]);
        float s = 0.f;
        #pragma unroll
        for (int u = 0; u < 8; ++u) {
            const float4 a = pp[u];
            s += (a.x + a.y) + (a.z + a.w);
        }
        if ((tid & 63) == 0) yp[SEQ - 1] = s + b0;
    }
}

extern "C" void kernel_launch(void* const* d_in, const int* in_sizes, int n_in,
                              void* d_out, int out_size, void* d_ws, size_t ws_size,
                              hipStream_t stream) {
    const float* x      = (const float*)d_in[0];
    const float* h0     = (const float*)d_in[1];
    const float* W_ih   = (const float*)d_in[2];
    const float* W_hh   = (const float*)d_in[3];
    const float* W_hh_b = (const float*)d_in[4];
    const float* b_h    = (const float*)d_in[5];
    const float* W      = (const float*)d_in[6];
    const float* bias   = (const float*)d_in[7];
    const int*   ctx    = (const int*)d_in[8];

    float* y  = (float*)d_out;                // (BATCH*SEQ,) = y[:,:,0]
    float* hs = y + (size_t)BATCH * SEQ;      // (BATCH, SEQ, HID) = out

    rnn_scan_kernel<<<BATCH, 512, 0, stream>>>(x, h0, W_ih, W_hh, W_hh_b,
                                               b_h, ctx, W, bias, hs, y);
}

// Round 3
// 1578.550 us; speedup vs baseline: 1.3128x; 1.3128x over previous
//
#include <hip/hip_runtime.h>
#include <math.h>

#define SEQ   2048
#define BATCH 128
#define HID   256
#define NCH   16   // k-chunks
#define KCH   16   // floats per chunk
#define VST   20   // chunk stride in floats (80B): 16 chunk bases -> 8 bank
                   // quads x 2 addrs = 2-way max on b128 reads (free, m136)

// dst = src's value from lane (lane perm pattern) via DPP (VALU pipe, no LDS).
// 0xB1 = quad_perm [1,0,3,2] (xor1); 0x4E = quad_perm [2,3,0,1] (xor2);
// 0x124/0x128 = row_ror:4/8 within each 16-lane row.
// ror8 == xor8 within 16 lanes. ror4 == xor4 AFTER the ror8 fold, because
// lanes l and l^8 are then bitwise duplicates (lane's ror4 source is either
// the true xor4 partner or its ^8 duplicate). Numerics validated rounds 0-2
// (absmax 2.98e-08 across all variants).
template <int CTRL>
__device__ __forceinline__ float dpp_mov(float x) {
    return __int_as_float(__builtin_amdgcn_update_dpp(
        __float_as_int(x), __float_as_int(x), CTRL, 0xF, 0xF, false));
}

// One block (1024 threads, 16 waves, 4 waves/SIMD) per batch element. fp32.
// ROUND-3 STRUCTURE CHANGE: grid is pinned at BATCH=128 blocks (the h-
// recurrence forbids splitting HID across blocks), so per-CU TLP must come
// from block size. 512 threads = 2 waves/SIMD could not hide the step's
// serial tail (ds_read latency -> DPP reduce chain -> expf -> LDS write ->
// barrier, ~700 cyc measured stall at VALUBusy 52%). 1024 threads = 4
// waves/SIMD: same 512-cyc FMA issue floor per SIMD per step, 2x the waves
// to overlap each wave's tail. Per-thread work halves: 4 rows x 1 chunk.
//
// Thread (R=tid>>4, l=tid&15, l3=tid&3): k-chunk [16l,16l+16), rows
// 4R+(l3^j), j=0..3 -> 64 weight fp32 in VGPRs (wreg[4][4]; ~105 VGPR total,
// fits the 128 cap for 4 waves/SIMD; waves_per_eu(4,4) pins the allocator).
// Reduce all-DPP: fold ror8 (chunks l<->l^8), fold ror4 (chunks l<->l^4, dup
// trick above) -> lanes l,l^4,l^8,l^12 bitwise-identical; then XOR transpose
// over q[0..3] via quad_perm xor1/xor2 (touch lane bits 0,1 only, preserving
// the dup) -> every lane holds the full dot of row 4R+l3; lanes (tid&12)==0
// are the representatives for LDS/global writes.
// v = 2h-1 fp32, double-buffered, ONE __syncthreads()/step; K-loop unrolled
// x2 so buffer pointers are static. y head stays a separate kernel (~50 us;
// rounds 1-2 proved in-scan fusion costs ~650 us of serial-tail time).
__global__ __launch_bounds__(1024) __attribute__((amdgpu_waves_per_eu(4, 4)))
void rnn_scan_kernel(const float* __restrict__ x,        // (SEQ, BATCH)
                     const float* __restrict__ h0,       // (BATCH, HID)
                     const float* __restrict__ W_ih,     // (HID, 1)
                     const float* __restrict__ W_hh,     // (HID, HID)
                     const float* __restrict__ W_hh_b,   // (HID, HID)
                     const float* __restrict__ b_h,      // (HID,)
                     const int*   __restrict__ context,  // scalar
                     float*       __restrict__ out_hs)   // (BATCH, SEQ, HID)
{
    const int b   = blockIdx.x;
    const int tid = threadIdx.x;
    const int R   = tid >> 4;    // row-group: rows [4R, 4R+4)
    const int l   = tid & 15;    // k-chunk index
    const int l3  = tid & 3;
    const int row = 4 * R + l3;  // row this thread represents after reduce
    const bool rep = (tid & 12) == 0;   // one representative lane per row

    __shared__ __align__(16) float v_lds[2][NCH * VST];
    __shared__ float x_lds[SEQ];

    for (int t = tid; t < SEQ; t += 1024)
        x_lds[t] = x[t * BATCH + b];

    const float ctx = (float)context[0];

    // wreg[j][c] = W_eff[4R + (l3^j)][16l + 4c .. +3]  (XOR-ordered rows)
    float4 wreg[4][4];
    #pragma unroll
    for (int j = 0; j < 4; ++j) {
        const int rj = 4 * R + (l3 ^ j);
        const float* wp = W_hh   + (size_t)rj * HID + KCH * l;
        const float* bp = W_hh_b + (size_t)rj * HID + KCH * l;
        #pragma unroll
        for (int c = 0; c < 4; ++c) {
            const float4 a = *(const float4*)(wp + 4 * c);
            const float4 d = *(const float4*)(bp + 4 * c);
            wreg[j][c] = make_float4(a.x + ctx * d.x, a.y + ctx * d.y,
                                     a.z + ctx * d.z, a.w + ctx * d.w);
        }
    }

    const float winj = W_ih[row];
    const float bhj  = b_h[row];

    // voff: rows 16w..16w+15 of a wave's reps map to 16 consecutive floats
    // at 20w -> 16 distinct banks, conflict-free.
    const int voff = VST * (row >> 4) + (row & 15);
    if (rep)
        v_lds[0][voff] = 2.f * h0[(size_t)b * HID + row] - 1.f;

    float* outp = out_hs + (size_t)b * SEQ * HID + row;

    const float4* vr0 = (const float4*)(v_lds[0] + VST * l);  // 80B-stride
    const float4* vr1 = (const float4*)(v_lds[1] + VST * l);

    __syncthreads();  // v[0] + x_lds ready

    auto step = [&](int t, const float4* __restrict__ vr, float* __restrict__ vw) {
        float q[4] = {0.f, 0.f, 0.f, 0.f};
        #pragma unroll
        for (int c = 0; c < 4; ++c) {
            const float4 v4 = vr[c];
            #pragma unroll
            for (int j = 0; j < 4; ++j) {
                const float4 w = wreg[j][c];
                q[j] += w.x * v4.x;
                q[j] += w.y * v4.y;
                q[j] += w.z * v4.z;
                q[j] += w.w * v4.w;
            }
        }
        // Chunk folds: l<->l^8 (ror8), then l<->l^4 (ror4 == xor4 via dup).
        #pragma unroll
        for (int j = 0; j < 4; ++j) q[j] += dpp_mov<0x128>(q[j]);
        #pragma unroll
        for (int j = 0; j < 4; ++j) q[j] += dpp_mov<0x124>(q[j]);
        // XOR transpose-reduce over the 4 rows (lane bits 0,1 only).
        q[0] += dpp_mov<0xB1>(q[1]);
        q[2] += dpp_mov<0xB1>(q[3]);
        q[0] += dpp_mov<0x4E>(q[2]);
        // q[0] = full dot for row 4R + l3 (every lane; 4x dup per row)

        const float pre = q[0] + bhj + x_lds[t] * winj;
        const float h = 1.f / (1.f + __expf(-pre));
        if (rep) {
            vw[voff] = 2.f * h - 1.f;             // 16 lanes/wave, 16 banks
            outp[(size_t)t * HID] = h;            // 16 lanes/wave, 64B runs
        }
        __syncthreads();  // v for t+1 ready; buffer t fully read before reuse
    };

    for (int t = 0; t < SEQ; t += 2) {
        step(t,     vr0, v_lds[1]);
        step(t + 1, vr1, v_lds[0]);
    }
}

// y[r] = dot(hs[r,:], W[0,:]) + bias[0]. 16 lanes/row, 4 rows/wave; each lane
// covers 16 floats; shfl-xor tree over 16 lanes. (Validated rounds 0/4.)
__global__ __launch_bounds__(256, 4)
void head_kernel(const float* __restrict__ hs,   // (BATCH*SEQ, HID)
                 const float* __restrict__ W,    // (OUTD, HID)
                 const float* __restrict__ bias, // (OUTD,)
                 float*       __restrict__ y)    // (BATCH*SEQ,)
{
    const int tid  = threadIdx.x;
    const int lane = tid & 63;
    const int sub  = lane & 15;
    const int rsub = lane >> 4;

    float4 w0[4];
    #pragma unroll
    for (int u = 0; u < 4; ++u)
        w0[u] = *(const float4*)(W + 4 * (16 * u + sub));
    const float b0 = bias[0];

    const int gwave = (blockIdx.x * blockDim.x + tid) >> 6;
    const int nw    = (gridDim.x * blockDim.x) >> 6;
    const int nq    = (BATCH * SEQ) >> 2;

    for (int q = gwave; q < nq; q += nw) {
        const int rrow = q * 4 + rsub;
        const float* rp = hs + (size_t)rrow * HID;
        float s = 0.f;
        #pragma unroll
        for (int u = 0; u < 4; ++u) {
            const float4 hv = *(const float4*)(rp + 4 * (16 * u + sub));
            s += hv.x * w0[u].x + hv.y * w0[u].y +
                 hv.z * w0[u].z + hv.w * w0[u].w;
        }
        s += __shfl_xor(s, 1, 64);
        s += __shfl_xor(s, 2, 64);
        s += __shfl_xor(s, 4, 64);
        s += __shfl_xor(s, 8, 64);
        if (sub == 0) y[rrow] = s + b0;
    }
}

extern "C" void kernel_launch(void* const* d_in, const int* in_sizes, int n_in,
                              void* d_out, int out_size, void* d_ws, size_t ws_size,
                              hipStream_t stream) {
    const float* x      = (const float*)d_in[0];
    const float* h0     = (const float*)d_in[1];
    const float* W_ih   = (const float*)d_in[2];
    const float* W_hh   = (const float*)d_in[3];
    const float* W_hh_b = (const float*)d_in[4];
    const float* b_h    = (const float*)d_in[5];
    const float* W      = (const float*)d_in[6];
    const float* bias   = (const float*)d_in[7];
    const int*   ctx    = (const int*)d_in[8];

    float* y  = (float*)d_out;                // (BATCH*SEQ,) = y[:,:,0]
    float* hs = y + (size_t)BATCH * SEQ;      // (BATCH, SEQ, HID) = out

    rnn_scan_kernel<<<BATCH, 1024, 0, stream>>>(x, h0, W_ih, W_hh, W_hh_b,
                                                b_h, ctx, hs);
    head_kernel<<<2048, 256, 0, stream>>>(hs, W, bias, y);
}